// Round 1
// baseline (576.770 us; speedup 1.0000x reference)
//
#include <hip/hip_runtime.h>
#include <hip/hip_bf16.h>

#define NODES 50000
#define NEDGE 800000
#define NPRED 200000

// ---------------------------------------------------------------------------
// CSR build: deg count -> 3-phase exclusive scan -> slot fill
// ---------------------------------------------------------------------------
__global__ __launch_bounds__(256) void deg_init(int* __restrict__ deg, int* __restrict__ fillc, int n) {
    int i = blockIdx.x * 256 + threadIdx.x;
    if (i < n) { deg[i] = 1; fillc[i] = 0; }   // deg starts at 1 (self loop)
}

__global__ __launch_bounds__(256) void deg_count(const int* __restrict__ dstv, int* __restrict__ deg, int E) {
    int e = blockIdx.x * 256 + threadIdx.x;
    if (e < E) atomicAdd(&deg[dstv[e]], 1);
}

// phase A: per-block (1024 elems) sums of (deg-1)
__global__ __launch_bounds__(256) void scan_bsum(const int* __restrict__ deg, int* __restrict__ bsum, int n) {
    __shared__ int s[256];
    int t = threadIdx.x, b = blockIdx.x;
    int base = b * 1024 + t * 4;
    int sum = 0;
#pragma unroll
    for (int j = 0; j < 4; ++j) { int i = base + j; if (i < n) sum += deg[i] - 1; }
    s[t] = sum; __syncthreads();
    for (int off = 128; off >= 1; off >>= 1) {
        if (t < off) s[t] += s[t + off];
        __syncthreads();
    }
    if (t == 0) bsum[b] = s[0];
}

// phase B: single wave scans block sums (nb <= 64)
__global__ void scan_boff(const int* __restrict__ bsum, int* __restrict__ boff, int nb,
                          int* __restrict__ row_ptr, int n) {
    int t = threadIdx.x;           // 64 threads
    int v = (t < nb) ? bsum[t] : 0;
    int orig = v;
    for (int off = 1; off < 64; off <<= 1) {
        int u = __shfl_up(v, off, 64);
        if (t >= off) v += u;
    }
    boff[t] = v - orig;            // exclusive
    if (t == 63) row_ptr[n] = v;   // total = E
}

// phase C: re-scan within block, write row_ptr + dinv
__global__ __launch_bounds__(256) void scan_write(const int* __restrict__ deg, const int* __restrict__ boff,
                                                  int* __restrict__ row_ptr, float* __restrict__ dinv, int n) {
    __shared__ int s[256];
    int t = threadIdx.x, b = blockIdx.x;
    int base = b * 1024 + t * 4;
    int v[4]; int sum = 0;
#pragma unroll
    for (int j = 0; j < 4; ++j) { int i = base + j; v[j] = (i < n) ? (deg[i] - 1) : 0; sum += v[j]; }
    s[t] = sum; __syncthreads();
    for (int off = 1; off < 256; off <<= 1) {
        int u = (t >= off) ? s[t - off] : 0;
        __syncthreads();
        s[t] += u;
        __syncthreads();
    }
    int run = s[t] - sum + boff[b];
#pragma unroll
    for (int j = 0; j < 4; ++j) {
        int i = base + j;
        if (i < n) { row_ptr[i] = run; run += v[j]; dinv[i] = rsqrtf((float)deg[i]); }
    }
}

__global__ __launch_bounds__(256) void csr_fill(const int* __restrict__ ei, const int* __restrict__ row_ptr,
                                                int* __restrict__ fillc, int* __restrict__ colv, int E) {
    int e = blockIdx.x * 256 + threadIdx.x;
    if (e < E) {
        int s = ei[e];          // src
        int d = ei[E + e];      // dst
        int p = row_ptr[d] + atomicAdd(&fillc[d], 1);
        colv[p] = s;
    }
}

// ---------------------------------------------------------------------------
// GEMM: H[M,N] = X[M,128] @ W[128,N].  64x64 tile, 256 thr, 4x4 per thread.
// LDS = 32KB + 32KB -> 2 blocks/CU.
// ---------------------------------------------------------------------------
__global__ __launch_bounds__(256) void gemm64(const float* __restrict__ X, const float* __restrict__ W,
                                              float* __restrict__ H, int M, int N) {
    __shared__ float xs[64][128];
    __shared__ float ws[128][64];
    const int tid = threadIdx.x;
    const int m0 = blockIdx.x * 64;
    const int n0 = blockIdx.y * 64;
    for (int idx = tid * 4; idx < 128 * 64; idx += 1024) {
        int k = idx >> 6, n = idx & 63;
        *(float4*)&ws[k][n] = *(const float4*)&W[k * N + n0 + n];
    }
    for (int idx = tid * 4; idx < 64 * 128; idx += 1024) {
        int r = idx >> 7, k = idx & 127;
        int row = m0 + r; if (row > M - 1) row = M - 1;   // clamp; stores guarded
        *(float4*)&xs[r][k] = *(const float4*)&X[row * 128 + k];
    }
    __syncthreads();
    const int c0 = (tid & 15) * 4;
    const int r0 = (tid >> 4) * 4;
    float4 acc[4] = {};
    for (int k = 0; k < 128; k += 4) {
        float4 w0 = *(const float4*)&ws[k + 0][c0];
        float4 w1 = *(const float4*)&ws[k + 1][c0];
        float4 w2 = *(const float4*)&ws[k + 2][c0];
        float4 w3 = *(const float4*)&ws[k + 3][c0];
#pragma unroll
        for (int r = 0; r < 4; ++r) {
            float4 fv = *(const float4*)&xs[r0 + r][k];
            acc[r].x += fv.x * w0.x + fv.y * w1.x + fv.z * w2.x + fv.w * w3.x;
            acc[r].y += fv.x * w0.y + fv.y * w1.y + fv.z * w2.y + fv.w * w3.y;
            acc[r].z += fv.x * w0.z + fv.y * w1.z + fv.z * w2.z + fv.w * w3.z;
            acc[r].w += fv.x * w0.w + fv.y * w1.w + fv.z * w2.w + fv.w * w3.w;
        }
    }
#pragma unroll
    for (int r = 0; r < 4; ++r) {
        int row = m0 + r0 + r;
        if (row < M) *(float4*)&H[row * N + n0 + c0] = acc[r];
    }
}

// ---------------------------------------------------------------------------
// Aggregation: out[d] = (sum_{s->d} h[s]*dinv[s] + h[d]*dinv[d]) * dinv[d] + bias
// One block per node, C threads (C = channels).
// ---------------------------------------------------------------------------
template <int C, bool RELU>
__global__ __launch_bounds__(C) void agg_kernel(const float* __restrict__ h, const int* __restrict__ row_ptr,
                                                const int* __restrict__ colv, const float* __restrict__ dinv,
                                                const float* __restrict__ bias, float* __restrict__ out) {
    int d = blockIdx.x;
    int c = threadIdx.x;
    float dv = dinv[d];
    float acc = h[d * C + c] * dv;         // self loop (x dv again at the end)
    int beg = row_ptr[d], end = row_ptr[d + 1];
    int i = beg;
    for (; i + 1 < end; i += 2) {
        int s0 = colv[i], s1 = colv[i + 1];
        float w0 = dinv[s0], w1 = dinv[s1];
        acc += h[s0 * C + c] * w0;
        acc += h[s1 * C + c] * w1;
    }
    if (i < end) {
        int s0 = colv[i];
        acc += h[s0 * C + c] * dinv[s0];
    }
    float o = acc * dv + bias[c];
    if (RELU) o = fmaxf(o, 0.0f);
    out[d * C + c] = o;
}

// ---------------------------------------------------------------------------
// Decode: pred[e] = relu(concat(z[src],z[dst]) @ Wa + ba) @ Wb + bb
// Gathered GEMM, 64 edges/block, Wa staged in two 64-col LDS passes (64KB total),
// fused epilogue (relu + Wb dot + lane reduction).
// ---------------------------------------------------------------------------
__global__ __launch_bounds__(256) void decode_kernel(const float* __restrict__ z, const int* __restrict__ src,
                                                     const int* __restrict__ dst, const float* __restrict__ Wa,
                                                     const float* __restrict__ ba, const float* __restrict__ Wb,
                                                     const float* __restrict__ bb, float* __restrict__ out) {
    __shared__ float ws[128][64];
    __shared__ float fs[64][128];
    const int tid = threadIdx.x;
    const int e0 = blockIdx.x * 64;
    // gather feature tile: fs[e][0:64] = z[src[e]], fs[e][64:128] = z[dst[e]]
    for (int idx = tid; idx < 64 * 32; idx += 256) {
        int e = idx >> 5, q = idx & 31;
        int node = (q < 16) ? src[e0 + e] : dst[e0 + e];
        int qq = q & 15;
        *(float4*)&fs[e][q * 4] = *(const float4*)&z[node * 64 + qq * 4];
    }
    const int c0 = (tid & 15) * 4;
    const int r0 = (tid >> 4) * 4;
    float pacc[4] = {0.f, 0.f, 0.f, 0.f};
    for (int pass = 0; pass < 2; ++pass) {
        __syncthreads();   // pass0: fs ready before compute; pass1: prev compute done before ws overwrite
        for (int idx = tid * 4; idx < 128 * 64; idx += 1024) {
            int k = idx >> 6, n = idx & 63;
            *(float4*)&ws[k][n] = *(const float4*)&Wa[k * 128 + pass * 64 + n];
        }
        __syncthreads();
        float4 acc[4] = {};
        for (int k = 0; k < 128; k += 4) {
            float4 w0 = *(const float4*)&ws[k + 0][c0];
            float4 w1 = *(const float4*)&ws[k + 1][c0];
            float4 w2 = *(const float4*)&ws[k + 2][c0];
            float4 w3 = *(const float4*)&ws[k + 3][c0];
#pragma unroll
            for (int r = 0; r < 4; ++r) {
                float4 fv = *(const float4*)&fs[r0 + r][k];
                acc[r].x += fv.x * w0.x + fv.y * w1.x + fv.z * w2.x + fv.w * w3.x;
                acc[r].y += fv.x * w0.y + fv.y * w1.y + fv.z * w2.y + fv.w * w3.y;
                acc[r].z += fv.x * w0.z + fv.y * w1.z + fv.z * w2.z + fv.w * w3.z;
                acc[r].w += fv.x * w0.w + fv.y * w1.w + fv.z * w2.w + fv.w * w3.w;
            }
        }
        int ch = pass * 64 + c0;
        float4 ba4 = *(const float4*)&ba[ch];
        float4 wb4 = *(const float4*)&Wb[ch];
#pragma unroll
        for (int r = 0; r < 4; ++r) {
            float h0 = fmaxf(acc[r].x + ba4.x, 0.f);
            float h1 = fmaxf(acc[r].y + ba4.y, 0.f);
            float h2 = fmaxf(acc[r].z + ba4.z, 0.f);
            float h3 = fmaxf(acc[r].w + ba4.w, 0.f);
            pacc[r] += h0 * wb4.x + h1 * wb4.y + h2 * wb4.z + h3 * wb4.w;
        }
    }
    // reduce over the 16 col-group lanes (consecutive lanes within the wave)
#pragma unroll
    for (int off = 8; off >= 1; off >>= 1) {
#pragma unroll
        for (int r = 0; r < 4; ++r) pacc[r] += __shfl_xor(pacc[r], off, 64);
    }
    if ((tid & 15) == 0) {
        float bbv = bb[0];
#pragma unroll
        for (int r = 0; r < 4; ++r) out[e0 + r0 + r] = pacc[r] + bbv;
    }
}

// ---------------------------------------------------------------------------
extern "C" void kernel_launch(void* const* d_in, const int* in_sizes, int n_in,
                              void* d_out, int out_size, void* d_ws, size_t ws_size,
                              hipStream_t stream) {
    const int N = NODES, E = NEDGE, P = NPRED;
    const float* x  = (const float*)d_in[0];
    const int*   ei = (const int*)d_in[1];
    const int*  pos = (const int*)d_in[2];
    const int*  neg = (const int*)d_in[3];
    const float* W1 = (const float*)d_in[4];
    const float* b1 = (const float*)d_in[5];
    const float* W2 = (const float*)d_in[6];
    const float* b2 = (const float*)d_in[7];
    const float* Wa = (const float*)d_in[8];
    const float* ba = (const float*)d_in[9];
    const float* Wb = (const float*)d_in[10];
    const float* bb = (const float*)d_in[11];
    float* out = (float*)d_out;

    char* w = (char*)d_ws;
    auto alloc = [&](size_t bytes) { char* p = w; w += (bytes + 255) & ~(size_t)255; return p; };
    int*   deg     = (int*)alloc((size_t)N * 4);
    int*   fillc   = (int*)alloc((size_t)N * 4);
    int*   row_ptr = (int*)alloc((size_t)(N + 1) * 4);
    int*   colv    = (int*)alloc((size_t)E * 4);
    float* dinv    = (float*)alloc((size_t)N * 4);
    int*   bsum    = (int*)alloc(64 * 4);
    int*   boff    = (int*)alloc(64 * 4);
    float* bufA    = (float*)alloc((size_t)N * 128 * 4);  // h1, then h2
    float* bufB    = (float*)alloc((size_t)N * 128 * 4);  // z1, then z

    const int nb = (N + 1023) / 1024;  // 49
    deg_init<<<(N + 255) / 256, 256, 0, stream>>>(deg, fillc, N);
    deg_count<<<(E + 255) / 256, 256, 0, stream>>>(ei + E, deg, E);
    scan_bsum<<<nb, 256, 0, stream>>>(deg, bsum, N);
    scan_boff<<<1, 64, 0, stream>>>(bsum, boff, nb, row_ptr, N);
    scan_write<<<nb, 256, 0, stream>>>(deg, boff, row_ptr, dinv, N);
    csr_fill<<<(E + 255) / 256, 256, 0, stream>>>(ei, row_ptr, fillc, colv, E);

    // layer 1: h1 = x @ W1 ; z1 = relu(agg(h1) + b1)
    dim3 g1((N + 63) / 64, 2);
    gemm64<<<g1, 256, 0, stream>>>(x, W1, bufA, N, 128);
    agg_kernel<128, true><<<N, 128, 0, stream>>>(bufA, row_ptr, colv, dinv, b1, bufB);

    // layer 2: h2 = z1 @ W2 ; z = agg(h2) + b2
    dim3 g2((N + 63) / 64, 1);
    gemm64<<<g2, 256, 0, stream>>>(bufB, W2, bufA, N, 64);
    agg_kernel<64, false><<<N, 64, 0, stream>>>(bufA, row_ptr, colv, dinv, b2, bufB);

    // decode pos + neg
    decode_kernel<<<P / 64, 256, 0, stream>>>(bufB, pos, pos + P, Wa, ba, Wb, bb, out);
    decode_kernel<<<P / 64, 256, 0, stream>>>(bufB, neg, neg + P, Wa, ba, Wb, bb, out + P);
}

// Round 2
// 377.640 us; speedup vs baseline: 1.5273x; 1.5273x over previous
//
#include <hip/hip_runtime.h>
#include <hip/hip_bf16.h>

#define NODES 50000
#define NEDGE 800000
#define NPRED 200000

typedef __attribute__((ext_vector_type(8))) short bf16x8;
typedef __attribute__((ext_vector_type(4))) float f32x4;

// ---------------------------------------------------------------------------
// CSR build: deg count -> 3-phase exclusive scan -> slot fill
// ---------------------------------------------------------------------------
__global__ __launch_bounds__(256) void deg_init(int* __restrict__ deg, int* __restrict__ fillc, int n) {
    int i = blockIdx.x * 256 + threadIdx.x;
    if (i < n) { deg[i] = 1; fillc[i] = 0; }   // deg starts at 1 (self loop)
}

__global__ __launch_bounds__(256) void deg_count(const int* __restrict__ dstv, int* __restrict__ deg, int E) {
    int e = blockIdx.x * 256 + threadIdx.x;
    if (e < E) atomicAdd(&deg[dstv[e]], 1);
}

__global__ __launch_bounds__(256) void scan_bsum(const int* __restrict__ deg, int* __restrict__ bsum, int n) {
    __shared__ int s[256];
    int t = threadIdx.x, b = blockIdx.x;
    int base = b * 1024 + t * 4;
    int sum = 0;
#pragma unroll
    for (int j = 0; j < 4; ++j) { int i = base + j; if (i < n) sum += deg[i] - 1; }
    s[t] = sum; __syncthreads();
    for (int off = 128; off >= 1; off >>= 1) {
        if (t < off) s[t] += s[t + off];
        __syncthreads();
    }
    if (t == 0) bsum[b] = s[0];
}

__global__ void scan_boff(const int* __restrict__ bsum, int* __restrict__ boff, int nb,
                          int* __restrict__ row_ptr, int n) {
    int t = threadIdx.x;           // 64 threads
    int v = (t < nb) ? bsum[t] : 0;
    int orig = v;
    for (int off = 1; off < 64; off <<= 1) {
        int u = __shfl_up(v, off, 64);
        if (t >= off) v += u;
    }
    boff[t] = v - orig;            // exclusive
    if (t == 63) row_ptr[n] = v;   // total = E
}

__global__ __launch_bounds__(256) void scan_write(const int* __restrict__ deg, const int* __restrict__ boff,
                                                  int* __restrict__ row_ptr, float* __restrict__ dinv, int n) {
    __shared__ int s[256];
    int t = threadIdx.x, b = blockIdx.x;
    int base = b * 1024 + t * 4;
    int v[4]; int sum = 0;
#pragma unroll
    for (int j = 0; j < 4; ++j) { int i = base + j; v[j] = (i < n) ? (deg[i] - 1) : 0; sum += v[j]; }
    s[t] = sum; __syncthreads();
    for (int off = 1; off < 256; off <<= 1) {
        int u = (t >= off) ? s[t - off] : 0;
        __syncthreads();
        s[t] += u;
        __syncthreads();
    }
    int run = s[t] - sum + boff[b];
#pragma unroll
    for (int j = 0; j < 4; ++j) {
        int i = base + j;
        if (i < n) { row_ptr[i] = run; run += v[j]; dinv[i] = rsqrtf((float)deg[i]); }
    }
}

__global__ __launch_bounds__(256) void csr_fill(const int* __restrict__ ei, const int* __restrict__ row_ptr,
                                                int* __restrict__ fillc, int* __restrict__ colv, int E) {
    int e = blockIdx.x * 256 + threadIdx.x;
    if (e < E) {
        int s = ei[e];          // src
        int d = ei[E + e];      // dst
        int p = row_ptr[d] + atomicAdd(&fillc[d], 1);
        colv[p] = s;
    }
}

// ---------------------------------------------------------------------------
// GEMM: H[M,N] = X[M,128] @ W[128,N].  64x64 tile, 256 thr, 4x4 per thread.
// ---------------------------------------------------------------------------
__global__ __launch_bounds__(256) void gemm64(const float* __restrict__ X, const float* __restrict__ W,
                                              float* __restrict__ H, int M, int N) {
    __shared__ float xs[64][128];
    __shared__ float ws[128][64];
    const int tid = threadIdx.x;
    const int m0 = blockIdx.x * 64;
    const int n0 = blockIdx.y * 64;
    for (int idx = tid * 4; idx < 128 * 64; idx += 1024) {
        int k = idx >> 6, n = idx & 63;
        *(float4*)&ws[k][n] = *(const float4*)&W[k * N + n0 + n];
    }
    for (int idx = tid * 4; idx < 64 * 128; idx += 1024) {
        int r = idx >> 7, k = idx & 127;
        int row = m0 + r; if (row > M - 1) row = M - 1;   // clamp; stores guarded
        *(float4*)&xs[r][k] = *(const float4*)&X[row * 128 + k];
    }
    __syncthreads();
    const int c0 = (tid & 15) * 4;
    const int r0 = (tid >> 4) * 4;
    float4 acc[4] = {};
    for (int k = 0; k < 128; k += 4) {
        float4 w0 = *(const float4*)&ws[k + 0][c0];
        float4 w1 = *(const float4*)&ws[k + 1][c0];
        float4 w2 = *(const float4*)&ws[k + 2][c0];
        float4 w3 = *(const float4*)&ws[k + 3][c0];
#pragma unroll
        for (int r = 0; r < 4; ++r) {
            float4 fv = *(const float4*)&xs[r0 + r][k];
            acc[r].x += fv.x * w0.x + fv.y * w1.x + fv.z * w2.x + fv.w * w3.x;
            acc[r].y += fv.x * w0.y + fv.y * w1.y + fv.z * w2.y + fv.w * w3.y;
            acc[r].z += fv.x * w0.z + fv.y * w1.z + fv.z * w2.z + fv.w * w3.z;
            acc[r].w += fv.x * w0.w + fv.y * w1.w + fv.z * w2.w + fv.w * w3.w;
        }
    }
#pragma unroll
    for (int r = 0; r < 4; ++r) {
        int row = m0 + r0 + r;
        if (row < M) *(float4*)&H[row * N + n0 + c0] = acc[r];
    }
}

// ---------------------------------------------------------------------------
// Aggregation (float4): out[d] = (sum_{s->d} h[s]*dinv[s] + h[d]*dinv[d]) * dinv[d] + b
// ---------------------------------------------------------------------------
template <int C, bool RELU>
__global__ __launch_bounds__(256) void agg_v4(const float* __restrict__ h, const int* __restrict__ row_ptr,
                                              const int* __restrict__ colv, const float* __restrict__ dinv,
                                              const float* __restrict__ bias, float* __restrict__ out) {
    constexpr int TPN = C / 4;          // threads per node
    constexpr int NPB = 256 / TPN;      // nodes per block
    int d = blockIdx.x * NPB + threadIdx.x / TPN;
    int c4 = (threadIdx.x % TPN) * 4;
    float dv = dinv[d];
    float4 self = *(const float4*)&h[(size_t)d * C + c4];
    float4 acc = { self.x * dv, self.y * dv, self.z * dv, self.w * dv };
    int i = row_ptr[d], end = row_ptr[d + 1];
    for (; i + 1 < end; i += 2) {
        int s0 = colv[i], s1 = colv[i + 1];
        float w0 = dinv[s0], w1 = dinv[s1];
        float4 h0 = *(const float4*)&h[(size_t)s0 * C + c4];
        float4 h1 = *(const float4*)&h[(size_t)s1 * C + c4];
        acc.x += h0.x * w0 + h1.x * w1;
        acc.y += h0.y * w0 + h1.y * w1;
        acc.z += h0.z * w0 + h1.z * w1;
        acc.w += h0.w * w0 + h1.w * w1;
    }
    if (i < end) {
        int s0 = colv[i];
        float w0 = dinv[s0];
        float4 h0 = *(const float4*)&h[(size_t)s0 * C + c4];
        acc.x += h0.x * w0; acc.y += h0.y * w0; acc.z += h0.z * w0; acc.w += h0.w * w0;
    }
    float4 b4 = *(const float4*)&bias[c4];
    float4 o = { acc.x * dv + b4.x, acc.y * dv + b4.y, acc.z * dv + b4.z, acc.w * dv + b4.w };
    if (RELU) {
        o.x = fmaxf(o.x, 0.f); o.y = fmaxf(o.y, 0.f);
        o.z = fmaxf(o.z, 0.f); o.w = fmaxf(o.w, 0.f);
    }
    *(float4*)&out[(size_t)d * C + c4] = o;
}

// ---------------------------------------------------------------------------
// Precompute for MFMA decode: z -> bf16 copy; Wa -> bf16 in B-fragment order.
// B frag for 16x16x32: lane holds B[k][n], n = lane&15, k = (lane>>4)*8 + j.
// perm[((nt*4+kt)*64 + lane)*8 + j] = bf16(Wa[(kt*32+(lane>>4)*8+j)*128 + nt*16+(lane&15)])
// ---------------------------------------------------------------------------
__global__ __launch_bounds__(256) void z_to_bf16(const float* __restrict__ z, unsigned short* __restrict__ zb, int n4) {
    int i = blockIdx.x * 256 + threadIdx.x;
    if (i < n4) {
        float4 v = *(const float4*)&z[i * 4];
        ushort4 u;
        __hip_bfloat16 b0 = __float2bfloat16(v.x); u.x = *(unsigned short*)&b0;
        __hip_bfloat16 b1 = __float2bfloat16(v.y); u.y = *(unsigned short*)&b1;
        __hip_bfloat16 b2 = __float2bfloat16(v.z); u.z = *(unsigned short*)&b2;
        __hip_bfloat16 b3 = __float2bfloat16(v.w); u.w = *(unsigned short*)&b3;
        *(ushort4*)&zb[i * 4] = u;
    }
}

__global__ __launch_bounds__(256) void wab_perm_kernel(const float* __restrict__ Wa, unsigned short* __restrict__ perm) {
    int t = blockIdx.x * 256 + threadIdx.x;   // 0..2047 (8 nt * 4 kt * 64 lanes)
    if (t >= 2048) return;
    int lane = t & 63;
    int kt = (t >> 6) & 3;
    int nt = t >> 8;
    int n = nt * 16 + (lane & 15);
    int k0 = kt * 32 + (lane >> 4) * 8;
#pragma unroll
    for (int j = 0; j < 8; ++j) {
        __hip_bfloat16 b = __float2bfloat16(Wa[(k0 + j) * 128 + n]);
        perm[t * 8 + j] = *(unsigned short*)&b;
    }
}

// ---------------------------------------------------------------------------
// MFMA decode: pred[e] = relu(concat(z[s],z[d]) @ Wa + ba) @ Wb + bb
// One wave = 32 edges (2 A-sets share each B fragment). No LDS.
// A frag: A[m=lane&15][k=(lane>>4)*8+j] -> 16B contiguous chunk of a zb row.
// C/D:    col = lane&15, row = (lane>>4)*4 + reg.
// Grid: 12500 waves total; waves [0,6250) -> pos, [6250,12500) -> neg.
// ---------------------------------------------------------------------------
__global__ __launch_bounds__(256) void decode_mfma(const unsigned short* __restrict__ zb,
                                                   const int* __restrict__ pos, const int* __restrict__ neg,
                                                   const unsigned short* __restrict__ perm,
                                                   const float* __restrict__ ba, const float* __restrict__ Wb,
                                                   const float* __restrict__ bb, float* __restrict__ out, int P) {
    int lane = threadIdx.x & 63;
    int w = blockIdx.x * 4 + (threadIdx.x >> 6);
    int half = (w >= 6250);
    const int* src = half ? neg : pos;
    float* o = out + (half ? P : 0);
    int e0 = (half ? (w - 6250) : w) * 32;
    int m = lane & 15, q = lane >> 4;
    int eA = e0 + m, eB = e0 + 16 + m;
    int sA = src[eA], dA = src[P + eA];
    int sB = src[eB], dB = src[P + eB];
    bf16x8 a0[4], a1[4];
    a0[0] = *(const bf16x8*)(zb + (size_t)sA * 64 + q * 8);
    a0[1] = *(const bf16x8*)(zb + (size_t)sA * 64 + 32 + q * 8);
    a0[2] = *(const bf16x8*)(zb + (size_t)dA * 64 + q * 8);
    a0[3] = *(const bf16x8*)(zb + (size_t)dA * 64 + 32 + q * 8);
    a1[0] = *(const bf16x8*)(zb + (size_t)sB * 64 + q * 8);
    a1[1] = *(const bf16x8*)(zb + (size_t)sB * 64 + 32 + q * 8);
    a1[2] = *(const bf16x8*)(zb + (size_t)dB * 64 + q * 8);
    a1[3] = *(const bf16x8*)(zb + (size_t)dB * 64 + 32 + q * 8);
    float p0[4] = {0.f, 0.f, 0.f, 0.f};
    float p1[4] = {0.f, 0.f, 0.f, 0.f};
#pragma unroll
    for (int nt = 0; nt < 8; ++nt) {
        f32x4 c0 = {0.f, 0.f, 0.f, 0.f};
        f32x4 c1 = {0.f, 0.f, 0.f, 0.f};
#pragma unroll
        for (int kt = 0; kt < 4; ++kt) {
            bf16x8 b = *(const bf16x8*)(perm + (size_t)((nt * 4 + kt) * 64 + lane) * 8);
            c0 = __builtin_amdgcn_mfma_f32_16x16x32_bf16(a0[kt], b, c0, 0, 0, 0);
            c1 = __builtin_amdgcn_mfma_f32_16x16x32_bf16(a1[kt], b, c1, 0, 0, 0);
        }
        int ch = nt * 16 + m;
        float bav = ba[ch], wbv = Wb[ch];
#pragma unroll
        for (int r = 0; r < 4; ++r) {
            p0[r] += fmaxf(c0[r] + bav, 0.f) * wbv;
            p1[r] += fmaxf(c1[r] + bav, 0.f) * wbv;
        }
    }
#pragma unroll
    for (int off = 8; off >= 1; off >>= 1) {
#pragma unroll
        for (int r = 0; r < 4; ++r) {
            p0[r] += __shfl_xor(p0[r], off, 64);
            p1[r] += __shfl_xor(p1[r], off, 64);
        }
    }
    if (m == 0) {
        float bbv = bb[0];
#pragma unroll
        for (int r = 0; r < 4; ++r) {
            o[e0 + q * 4 + r] = p0[r] + bbv;
            o[e0 + 16 + q * 4 + r] = p1[r] + bbv;
        }
    }
}

// ---------------------------------------------------------------------------
extern "C" void kernel_launch(void* const* d_in, const int* in_sizes, int n_in,
                              void* d_out, int out_size, void* d_ws, size_t ws_size,
                              hipStream_t stream) {
    const int N = NODES, E = NEDGE, P = NPRED;
    const float* x  = (const float*)d_in[0];
    const int*   ei = (const int*)d_in[1];
    const int*  pos = (const int*)d_in[2];
    const int*  neg = (const int*)d_in[3];
    const float* W1 = (const float*)d_in[4];
    const float* b1 = (const float*)d_in[5];
    const float* W2 = (const float*)d_in[6];
    const float* b2 = (const float*)d_in[7];
    const float* Wa = (const float*)d_in[8];
    const float* ba = (const float*)d_in[9];
    const float* Wb = (const float*)d_in[10];
    const float* bb = (const float*)d_in[11];
    float* out = (float*)d_out;

    char* w = (char*)d_ws;
    auto alloc = [&](size_t bytes) { char* p = w; w += (bytes + 255) & ~(size_t)255; return p; };
    int*   deg     = (int*)alloc((size_t)N * 4);
    int*   fillc   = (int*)alloc((size_t)N * 4);
    int*   row_ptr = (int*)alloc((size_t)(N + 1) * 4);
    int*   colv    = (int*)alloc((size_t)E * 4);
    float* dinv    = (float*)alloc((size_t)N * 4);
    int*   bsum    = (int*)alloc(64 * 4);
    int*   boff    = (int*)alloc(64 * 4);
    float* bufA    = (float*)alloc((size_t)N * 128 * 4);  // h1, then h2, then zb+perm
    float* bufB    = (float*)alloc((size_t)N * 128 * 4);  // z1, then z

    // zb/perm carved out of bufA (dead after agg2 reads h2)
    unsigned short* zb   = (unsigned short*)bufA;                       // N*64*2 = 6.4 MB
    unsigned short* perm = (unsigned short*)(bufA + (size_t)N * 64 / 2 + 64);  // 32 KB

    const int nb = (N + 1023) / 1024;  // 49
    deg_init<<<(N + 255) / 256, 256, 0, stream>>>(deg, fillc, N);
    deg_count<<<(E + 255) / 256, 256, 0, stream>>>(ei + E, deg, E);
    scan_bsum<<<nb, 256, 0, stream>>>(deg, bsum, N);
    scan_boff<<<1, 64, 0, stream>>>(bsum, boff, nb, row_ptr, N);
    scan_write<<<nb, 256, 0, stream>>>(deg, boff, row_ptr, dinv, N);
    csr_fill<<<(E + 255) / 256, 256, 0, stream>>>(ei, row_ptr, fillc, colv, E);

    // layer 1: h1 = x @ W1 ; z1 = relu(agg(h1) + b1)
    dim3 g1((N + 63) / 64, 2);
    gemm64<<<g1, 256, 0, stream>>>(x, W1, bufA, N, 128);
    agg_v4<128, true><<<N / 8, 256, 0, stream>>>(bufA, row_ptr, colv, dinv, b1, bufB);

    // layer 2: h2 = z1 @ W2 ; z = agg(h2) + b2
    dim3 g2((N + 63) / 64, 1);
    gemm64<<<g2, 256, 0, stream>>>(bufB, W2, bufA, N, 64);
    agg_v4<64, false><<<N / 16, 256, 0, stream>>>(bufA, row_ptr, colv, dinv, b2, bufB);

    // decode prep (bufA free now): z -> bf16, Wa -> bf16 fragment order
    z_to_bf16<<<(N * 64 / 4 + 255) / 256, 256, 0, stream>>>(bufB, zb, N * 64 / 4);
    wab_perm_kernel<<<8, 256, 0, stream>>>(Wa, perm);

    // fused pos+neg decode: 12500 waves = 3125 blocks
    decode_mfma<<<3125, 256, 0, stream>>>(zb, pos, neg, perm, ba, Wb, bb, out, P);
}

// Round 3
// 285.777 us; speedup vs baseline: 2.0183x; 1.3215x over previous
//
#include <hip/hip_runtime.h>
#include <hip/hip_bf16.h>

#define NODES 50000
#define NEDGE 800000
#define NPRED 200000

typedef __attribute__((ext_vector_type(8))) short bf16x8;
typedef __attribute__((ext_vector_type(8))) unsigned short u16x8;
typedef __attribute__((ext_vector_type(4))) float f32x4;

__device__ inline float bf2f(unsigned short u) {
    union { unsigned int i; float f; } v; v.i = ((unsigned int)u) << 16; return v.f;
}
__device__ inline unsigned short f2bf(float f) {
    __hip_bfloat16 b = __float2bfloat16(f);
    return *(unsigned short*)&b;
}

// ---------------------------------------------------------------------------
// CSR build: deg count -> 3-phase exclusive scan -> slot fill
// ---------------------------------------------------------------------------
__global__ __launch_bounds__(256) void deg_init(int* __restrict__ deg, int* __restrict__ fillc, int n) {
    int i = blockIdx.x * 256 + threadIdx.x;
    if (i < n) { deg[i] = 1; fillc[i] = 0; }   // deg starts at 1 (self loop)
}

__global__ __launch_bounds__(256) void deg_count(const int* __restrict__ dstv, int* __restrict__ deg, int E) {
    int e = blockIdx.x * 256 + threadIdx.x;
    if (e < E) atomicAdd(&deg[dstv[e]], 1);
}

__global__ __launch_bounds__(256) void scan_bsum(const int* __restrict__ deg, int* __restrict__ bsum, int n) {
    __shared__ int s[256];
    int t = threadIdx.x, b = blockIdx.x;
    int base = b * 1024 + t * 4;
    int sum = 0;
#pragma unroll
    for (int j = 0; j < 4; ++j) { int i = base + j; if (i < n) sum += deg[i] - 1; }
    s[t] = sum; __syncthreads();
    for (int off = 128; off >= 1; off >>= 1) {
        if (t < off) s[t] += s[t + off];
        __syncthreads();
    }
    if (t == 0) bsum[b] = s[0];
}

__global__ void scan_boff(const int* __restrict__ bsum, int* __restrict__ boff, int nb,
                          int* __restrict__ row_ptr, int n) {
    int t = threadIdx.x;           // 64 threads
    int v = (t < nb) ? bsum[t] : 0;
    int orig = v;
    for (int off = 1; off < 64; off <<= 1) {
        int u = __shfl_up(v, off, 64);
        if (t >= off) v += u;
    }
    boff[t] = v - orig;            // exclusive
    if (t == 63) row_ptr[n] = v;   // total = E
}

__global__ __launch_bounds__(256) void scan_write(const int* __restrict__ deg, const int* __restrict__ boff,
                                                  int* __restrict__ row_ptr, float* __restrict__ dinv, int n) {
    __shared__ int s[256];
    int t = threadIdx.x, b = blockIdx.x;
    int base = b * 1024 + t * 4;
    int v[4]; int sum = 0;
#pragma unroll
    for (int j = 0; j < 4; ++j) { int i = base + j; v[j] = (i < n) ? (deg[i] - 1) : 0; sum += v[j]; }
    s[t] = sum; __syncthreads();
    for (int off = 1; off < 256; off <<= 1) {
        int u = (t >= off) ? s[t - off] : 0;
        __syncthreads();
        s[t] += u;
        __syncthreads();
    }
    int run = s[t] - sum + boff[b];
#pragma unroll
    for (int j = 0; j < 4; ++j) {
        int i = base + j;
        if (i < n) { row_ptr[i] = run; run += v[j]; dinv[i] = rsqrtf((float)deg[i]); }
    }
}

__global__ __launch_bounds__(256) void csr_fill(const int* __restrict__ ei, const int* __restrict__ row_ptr,
                                                int* __restrict__ fillc, int* __restrict__ colv, int E) {
    int e = blockIdx.x * 256 + threadIdx.x;
    if (e < E) {
        int s = ei[e];          // src
        int d = ei[E + e];      // dst
        int p = row_ptr[d] + atomicAdd(&fillc[d], 1);
        colv[p] = s;
    }
}

// ---------------------------------------------------------------------------
// Weight permutation into MFMA B-fragment order (bf16).
// B frag for 16x16x32: lane holds B[k][n], n = lane&15, k = (lane>>4)*8 + j.
// One kernel builds pW1 (128x128), pW2 (128x64), pWa (128x128).
// ---------------------------------------------------------------------------
__global__ __launch_bounds__(256) void perm_all(const float* __restrict__ W1, const float* __restrict__ W2,
                                                const float* __restrict__ Wa,
                                                unsigned short* __restrict__ pW1,
                                                unsigned short* __restrict__ pW2,
                                                unsigned short* __restrict__ pWa) {
    int t = blockIdx.x * 256 + threadIdx.x;   // 0..5119
    if (t >= 5120) return;
    const float* W; unsigned short* P; int N;
    if (t < 2048)      { W = W1; P = pW1; N = 128; }
    else if (t < 3072) { W = W2; P = pW2; N = 64;  t -= 2048; }
    else               { W = Wa; P = pWa; N = 128; t -= 3072; }
    int lane = t & 63;
    int kt = (t >> 6) & 3;
    int nt = t >> 8;
    int n = nt * 16 + (lane & 15);
    int k0 = kt * 32 + (lane >> 4) * 8;
#pragma unroll
    for (int j = 0; j < 8; ++j) P[t * 8 + j] = f2bf(W[(k0 + j) * N + n]);
}

// ---------------------------------------------------------------------------
// MFMA GEMM: H[M, NT*16] (bf16) = X[M,128] @ W (pre-permuted bf16 frags).
// One wave = 16 rows, no LDS. A frag = 16B contiguous chunk of a row.
// AFP32: X is fp32, converted in-register (numerically same as pre-convert).
// ---------------------------------------------------------------------------
template <int NT, bool AFP32>
__global__ __launch_bounds__(256) void gemm_mfma(const void* __restrict__ Xv,
                                                 const unsigned short* __restrict__ perm,
                                                 unsigned short* __restrict__ H, int M) {
    int w = blockIdx.x * 4 + (threadIdx.x >> 6);
    int m0 = w * 16;
    if (m0 >= M) return;
    int lane = threadIdx.x & 63;
    int m = lane & 15, q = lane >> 4;
    size_t row = (size_t)(m0 + m);
    bf16x8 a[4];
    if (AFP32) {
        const float* X = (const float*)Xv;
#pragma unroll
        for (int kt = 0; kt < 4; ++kt) {
            float4 f0 = *(const float4*)&X[row * 128 + kt * 32 + q * 8];
            float4 f1 = *(const float4*)&X[row * 128 + kt * 32 + q * 8 + 4];
            bf16x8 av;
            av[0] = (short)f2bf(f0.x); av[1] = (short)f2bf(f0.y);
            av[2] = (short)f2bf(f0.z); av[3] = (short)f2bf(f0.w);
            av[4] = (short)f2bf(f1.x); av[5] = (short)f2bf(f1.y);
            av[6] = (short)f2bf(f1.z); av[7] = (short)f2bf(f1.w);
            a[kt] = av;
        }
    } else {
        const unsigned short* X = (const unsigned short*)Xv;
#pragma unroll
        for (int kt = 0; kt < 4; ++kt)
            a[kt] = *(const bf16x8*)&X[row * 128 + kt * 32 + q * 8];
    }
    const int N = NT * 16;
#pragma unroll
    for (int nt = 0; nt < NT; ++nt) {
        f32x4 c = {0.f, 0.f, 0.f, 0.f};
#pragma unroll
        for (int kt = 0; kt < 4; ++kt) {
            bf16x8 b = *(const bf16x8*)(perm + (size_t)((nt * 4 + kt) * 64 + lane) * 8);
            c = __builtin_amdgcn_mfma_f32_16x16x32_bf16(a[kt], b, c, 0, 0, 0);
        }
        // C/D: col = lane&15, row_in_tile = q*4 + r
#pragma unroll
        for (int r = 0; r < 4; ++r)
            H[(size_t)(m0 + q * 4 + r) * N + nt * 16 + m] = f2bf(c[r]);
    }
}

// ---------------------------------------------------------------------------
// Aggregation (bf16 gathers, fp32 accumulate, unroll-4 ILP):
// out[d] = (sum_{s->d} h[s]*dinv[s] + h[d]*dinv[d]) * dinv[d] + bias
// ---------------------------------------------------------------------------
template <int C, bool RELU>
__global__ __launch_bounds__(256) void agg_bf16(const unsigned short* __restrict__ h,
                                                const int* __restrict__ row_ptr, const int* __restrict__ colv,
                                                const float* __restrict__ dinv, const float* __restrict__ bias,
                                                unsigned short* __restrict__ out) {
    constexpr int TPN = C / 8;          // lanes per node
    constexpr int NPB = 256 / TPN;      // nodes per block
    int d = blockIdx.x * NPB + threadIdx.x / TPN;
    if (d >= NODES) return;
    int c8 = (threadIdx.x % TPN) * 8;
    float dv = dinv[d];
    float acc[8];
    u16x8 self = *(const u16x8*)&h[(size_t)d * C + c8];
#pragma unroll
    for (int j = 0; j < 8; ++j) acc[j] = bf2f(self[j]) * dv;
    int i = row_ptr[d], end = row_ptr[d + 1];
    for (; i + 3 < end; i += 4) {
        int s0 = colv[i], s1 = colv[i + 1], s2 = colv[i + 2], s3 = colv[i + 3];
        float w0 = dinv[s0], w1 = dinv[s1], w2 = dinv[s2], w3 = dinv[s3];
        u16x8 r0 = *(const u16x8*)&h[(size_t)s0 * C + c8];
        u16x8 r1 = *(const u16x8*)&h[(size_t)s1 * C + c8];
        u16x8 r2 = *(const u16x8*)&h[(size_t)s2 * C + c8];
        u16x8 r3 = *(const u16x8*)&h[(size_t)s3 * C + c8];
#pragma unroll
        for (int j = 0; j < 8; ++j)
            acc[j] += bf2f(r0[j]) * w0 + bf2f(r1[j]) * w1 + bf2f(r2[j]) * w2 + bf2f(r3[j]) * w3;
    }
    for (; i < end; ++i) {
        int s0 = colv[i];
        float w0 = dinv[s0];
        u16x8 r0 = *(const u16x8*)&h[(size_t)s0 * C + c8];
#pragma unroll
        for (int j = 0; j < 8; ++j) acc[j] += bf2f(r0[j]) * w0;
    }
    u16x8 ov;
#pragma unroll
    for (int j = 0; j < 8; ++j) {
        float o = acc[j] * dv + bias[c8 + j];
        if (RELU) o = fmaxf(o, 0.f);
        ov[j] = f2bf(o);
    }
    *(u16x8*)&out[(size_t)d * C + c8] = ov;
}

// ---------------------------------------------------------------------------
// MFMA decode: pred[e] = relu(concat(z[s],z[d]) @ Wa + ba) @ Wb + bb
// One wave = 32 edges (2 A-sets share each B fragment). No LDS.
// ---------------------------------------------------------------------------
__global__ __launch_bounds__(256) void decode_mfma(const unsigned short* __restrict__ zb,
                                                   const int* __restrict__ pos, const int* __restrict__ neg,
                                                   const unsigned short* __restrict__ perm,
                                                   const float* __restrict__ ba, const float* __restrict__ Wb,
                                                   const float* __restrict__ bb, float* __restrict__ out, int P) {
    int lane = threadIdx.x & 63;
    int w = blockIdx.x * 4 + (threadIdx.x >> 6);
    int half = (w >= 6250);
    const int* src = half ? neg : pos;
    float* o = out + (half ? P : 0);
    int e0 = (half ? (w - 6250) : w) * 32;
    int m = lane & 15, q = lane >> 4;
    int eA = e0 + m, eB = e0 + 16 + m;
    int sA = src[eA], dA = src[P + eA];
    int sB = src[eB], dB = src[P + eB];
    bf16x8 a0[4], a1[4];
    a0[0] = *(const bf16x8*)(zb + (size_t)sA * 64 + q * 8);
    a0[1] = *(const bf16x8*)(zb + (size_t)sA * 64 + 32 + q * 8);
    a0[2] = *(const bf16x8*)(zb + (size_t)dA * 64 + q * 8);
    a0[3] = *(const bf16x8*)(zb + (size_t)dA * 64 + 32 + q * 8);
    a1[0] = *(const bf16x8*)(zb + (size_t)sB * 64 + q * 8);
    a1[1] = *(const bf16x8*)(zb + (size_t)sB * 64 + 32 + q * 8);
    a1[2] = *(const bf16x8*)(zb + (size_t)dB * 64 + q * 8);
    a1[3] = *(const bf16x8*)(zb + (size_t)dB * 64 + 32 + q * 8);
    float p0[4] = {0.f, 0.f, 0.f, 0.f};
    float p1[4] = {0.f, 0.f, 0.f, 0.f};
#pragma unroll
    for (int nt = 0; nt < 8; ++nt) {
        f32x4 c0 = {0.f, 0.f, 0.f, 0.f};
        f32x4 c1 = {0.f, 0.f, 0.f, 0.f};
#pragma unroll
        for (int kt = 0; kt < 4; ++kt) {
            bf16x8 b = *(const bf16x8*)(perm + (size_t)((nt * 4 + kt) * 64 + lane) * 8);
            c0 = __builtin_amdgcn_mfma_f32_16x16x32_bf16(a0[kt], b, c0, 0, 0, 0);
            c1 = __builtin_amdgcn_mfma_f32_16x16x32_bf16(a1[kt], b, c1, 0, 0, 0);
        }
        int ch = nt * 16 + m;
        float bav = ba[ch], wbv = Wb[ch];
#pragma unroll
        for (int r = 0; r < 4; ++r) {
            p0[r] += fmaxf(c0[r] + bav, 0.f) * wbv;
            p1[r] += fmaxf(c1[r] + bav, 0.f) * wbv;
        }
    }
#pragma unroll
    for (int off = 8; off >= 1; off >>= 1) {
#pragma unroll
        for (int r = 0; r < 4; ++r) {
            p0[r] += __shfl_xor(p0[r], off, 64);
            p1[r] += __shfl_xor(p1[r], off, 64);
        }
    }
    if (m == 0) {
        float bbv = bb[0];
#pragma unroll
        for (int r = 0; r < 4; ++r) {
            o[e0 + q * 4 + r] = p0[r] + bbv;
            o[e0 + 16 + q * 4 + r] = p1[r] + bbv;
        }
    }
}

// ---------------------------------------------------------------------------
extern "C" void kernel_launch(void* const* d_in, const int* in_sizes, int n_in,
                              void* d_out, int out_size, void* d_ws, size_t ws_size,
                              hipStream_t stream) {
    const int N = NODES, E = NEDGE, P = NPRED;
    const float* x  = (const float*)d_in[0];
    const int*   ei = (const int*)d_in[1];
    const int*  pos = (const int*)d_in[2];
    const int*  neg = (const int*)d_in[3];
    const float* W1 = (const float*)d_in[4];
    const float* b1 = (const float*)d_in[5];
    const float* W2 = (const float*)d_in[6];
    const float* b2 = (const float*)d_in[7];
    const float* Wa = (const float*)d_in[8];
    const float* ba = (const float*)d_in[9];
    const float* Wb = (const float*)d_in[10];
    const float* bb = (const float*)d_in[11];
    float* out = (float*)d_out;

    char* w = (char*)d_ws;
    auto alloc = [&](size_t bytes) { char* p = w; w += (bytes + 255) & ~(size_t)255; return p; };
    int*   deg     = (int*)alloc((size_t)N * 4);
    int*   fillc   = (int*)alloc((size_t)N * 4);
    int*   row_ptr = (int*)alloc((size_t)(N + 1) * 4);
    int*   colv    = (int*)alloc((size_t)E * 4);
    float* dinv    = (float*)alloc((size_t)N * 4);
    int*   bsum    = (int*)alloc(64 * 4);
    int*   boff    = (int*)alloc(64 * 4);
    unsigned short* h1b = (unsigned short*)alloc((size_t)N * 128 * 2);  // 12.8 MB
    unsigned short* z1b = (unsigned short*)alloc((size_t)N * 128 * 2);  // 12.8 MB
    unsigned short* h2b = (unsigned short*)alloc((size_t)N * 64 * 2);   // 6.4 MB
    unsigned short* zb  = (unsigned short*)alloc((size_t)N * 64 * 2);   // 6.4 MB
    unsigned short* pW1 = (unsigned short*)alloc(2048 * 8 * 2);         // 32 KB
    unsigned short* pW2 = (unsigned short*)alloc(1024 * 8 * 2);         // 16 KB
    unsigned short* pWa = (unsigned short*)alloc(2048 * 8 * 2);         // 32 KB

    const int nb = (N + 1023) / 1024;  // 49
    deg_init<<<(N + 255) / 256, 256, 0, stream>>>(deg, fillc, N);
    deg_count<<<(E + 255) / 256, 256, 0, stream>>>(ei + E, deg, E);
    scan_bsum<<<nb, 256, 0, stream>>>(deg, bsum, N);
    scan_boff<<<1, 64, 0, stream>>>(bsum, boff, nb, row_ptr, N);
    scan_write<<<nb, 256, 0, stream>>>(deg, boff, row_ptr, dinv, N);
    csr_fill<<<(E + 255) / 256, 256, 0, stream>>>(ei, row_ptr, fillc, colv, E);

    perm_all<<<20, 256, 0, stream>>>(W1, W2, Wa, pW1, pW2, pWa);

    // layer 1: h1 = bf16(x @ W1) ; z1 = bf16(relu(agg(h1) + b1))
    gemm_mfma<8, true><<<782, 256, 0, stream>>>(x, pW1, h1b, N);
    agg_bf16<128, true><<<N / 16, 256, 0, stream>>>(h1b, row_ptr, colv, dinv, b1, z1b);

    // layer 2: h2 = bf16(z1 @ W2) ; z = bf16(agg(h2) + b2)
    gemm_mfma<4, false><<<782, 256, 0, stream>>>(z1b, pW2, h2b, N);
    agg_bf16<64, false><<<(N + 31) / 32, 256, 0, stream>>>(h2b, row_ptr, colv, dinv, b2, zb);

    // fused pos+neg decode: 12500 waves = 3125 blocks
    decode_mfma<<<3125, 256, 0, stream>>>(zb, pos, neg, pWa, ba, Wb, bb, out, P);
}